// Round 3
// baseline (767.175 us; speedup 1.0000x reference)
//
#include <hip/hip_runtime.h>

#define D 128
#define NSPLIT 4
#define SPLITW 32

// ---- CSR build ----------------------------------------------------------

__global__ __launch_bounds__(256) void deg_kernel(const int* __restrict__ dst,
                                                  int* __restrict__ deg, int E) {
  int e = blockIdx.x * 256 + threadIdx.x;
  if (e < E) atomicAdd(&deg[dst[e]], 1);
}

// Single-block exclusive scan of deg -> offsets/cursor, fused dinv = rsqrt(1+deg).
__global__ __launch_bounds__(1024) void scan_kernel(const int* __restrict__ deg,
                                                    int* __restrict__ offsets,
                                                    int* __restrict__ cursor,
                                                    float* __restrict__ dinv, int N) {
  __shared__ int tsum[1024];
  int t = threadIdx.x;
  int chunk = (N + 1023) / 1024;
  int beg = t * chunk;
  int end = min(beg + chunk, N);
  int s = 0;
  for (int i = beg; i < end; ++i) s += deg[i];
  tsum[t] = s;
  __syncthreads();
  for (int off = 1; off < 1024; off <<= 1) {
    int v = (t >= off) ? tsum[t - off] : 0;
    __syncthreads();
    tsum[t] += v;
    __syncthreads();
  }
  int run = (t == 0) ? 0 : tsum[t - 1];
  for (int i = beg; i < end; ++i) {
    int dg = deg[i];
    offsets[i] = run;
    cursor[i] = run;
    dinv[i] = rsqrtf(1.0f + (float)dg);
    run += dg;
  }
  if (t == 1023) offsets[N] = run;
}

__global__ __launch_bounds__(256) void place_kernel(const int* __restrict__ src,
                                                    const int* __restrict__ dst,
                                                    const float* __restrict__ dinv,
                                                    int* __restrict__ cursor,
                                                    int2* __restrict__ csr, int E) {
  int e = blockIdx.x * 256 + threadIdx.x;
  if (e >= E) return;
  int s = src[e];
  int d = dst[e];
  int pos = atomicAdd(&cursor[d], 1);
  int2 p;
  p.x = s;
  p.y = __float_as_int(dinv[s] * dinv[d]);
  csr[pos] = p;
}

// ---- GEMM: H4[c/32][N][32] = X[N,128] @ W[128,128] (feature-split out) ----
// 256 thr/block, 32 rows/block. Thread: 8 rows x 2 adjacent cols.
// X-tile LDS reads are wave-uniform broadcasts -> VALU-bound.

__global__ __launch_bounds__(256) void gemm_kernel(const float* __restrict__ X,
                                                   const float* __restrict__ W,
                                                   float* __restrict__ H4, int N) {
  __shared__ float xs[32 * D];
  int row0 = blockIdx.x * 32;
  #pragma unroll
  for (int jj = 0; jj < 4; ++jj) {
    int f4 = threadIdx.x + jj * 256;
    int r = f4 >> 5;
    float4 v = make_float4(0.f, 0.f, 0.f, 0.f);
    if (row0 + r < N) v = *reinterpret_cast<const float4*>(X + (size_t)row0 * D + (size_t)f4 * 4);
    *reinterpret_cast<float4*>(xs + f4 * 4) = v;
  }
  __syncthreads();

  int tx = threadIdx.x & 63;
  int ty = threadIdx.x >> 6;          // 0..3 -> rows ty*8..ty*8+7
  int c0 = tx * 2;
  float2 acc[8];
  #pragma unroll
  for (int r = 0; r < 8; ++r) acc[r] = make_float2(0.f, 0.f);
  const float* xbase = xs + ty * 8 * D;

  for (int k = 0; k < D; k += 4) {
    float2 w0 = *reinterpret_cast<const float2*>(W + (size_t)(k + 0) * D + c0);
    float2 w1 = *reinterpret_cast<const float2*>(W + (size_t)(k + 1) * D + c0);
    float2 w2 = *reinterpret_cast<const float2*>(W + (size_t)(k + 2) * D + c0);
    float2 w3 = *reinterpret_cast<const float2*>(W + (size_t)(k + 3) * D + c0);
    #pragma unroll
    for (int r = 0; r < 8; ++r) {
      float4 xv = *reinterpret_cast<const float4*>(xbase + r * D + k);
      acc[r].x = fmaf(xv.x, w0.x, acc[r].x); acc[r].y = fmaf(xv.x, w0.y, acc[r].y);
      acc[r].x = fmaf(xv.y, w1.x, acc[r].x); acc[r].y = fmaf(xv.y, w1.y, acc[r].y);
      acc[r].x = fmaf(xv.z, w2.x, acc[r].x); acc[r].y = fmaf(xv.z, w2.y, acc[r].y);
      acc[r].x = fmaf(xv.w, w3.x, acc[r].x); acc[r].y = fmaf(xv.w, w3.y, acc[r].y);
    }
  }

  int chunk = c0 >> 5;                 // which 32-col split
  int cin = c0 & 31;
  float* Hc = H4 + (size_t)chunk * N * SPLITW;
  #pragma unroll
  for (int r = 0; r < 8; ++r) {
    int row = row0 + ty * 8 + r;
    if (row < N) *reinterpret_cast<float2*>(Hc + (size_t)row * SPLITW + cin) = acc[r];
  }
}

// ---- Aggregation pass over one 32-feature split --------------------------
// Wave = one dst node; 2 groups of 32 lanes each take alternating edges.
// out[n, colOff+l] = (relu?)( sum_e Hp[src_e][l]*norm_e + Hp[n][l]*dinv^2 + bias )

__global__ __launch_bounds__(256) void agg32_kernel(const float* __restrict__ Hp,
                                                    const int* __restrict__ offsets,
                                                    const int2* __restrict__ csr,
                                                    const float* __restrict__ dinv,
                                                    const float* __restrict__ bias,
                                                    float* __restrict__ out,
                                                    int N, int colOff, int do_relu) {
  int n = blockIdx.x * 4 + (threadIdx.x >> 6);
  int lane = threadIdx.x & 63;
  int g = lane >> 5;
  int l = lane & 31;
  if (n >= N) return;
  int beg = offsets[n];
  int end = offsets[n + 1];

  float acc = 0.f;
  int j = beg + g;
  for (; j + 2 < end; j += 4) {      // this group's indices: j, j+2
    int2 p0 = csr[j];
    int2 p1 = csr[j + 2];
    float h0 = Hp[(size_t)p0.x * SPLITW + l];
    float h1 = Hp[(size_t)p1.x * SPLITW + l];
    acc = fmaf(h0, __int_as_float(p0.y), acc);
    acc = fmaf(h1, __int_as_float(p1.y), acc);
  }
  if (j < end) {
    int2 p0 = csr[j];
    float h0 = Hp[(size_t)p0.x * SPLITW + l];
    acc = fmaf(h0, __int_as_float(p0.y), acc);
  }

  acc += __shfl_xor(acc, 32);        // combine the two edge-groups

  if (g == 0) {
    float di = dinv[n];
    float v = fmaf(Hp[(size_t)n * SPLITW + l], di * di, acc) + bias[colOff + l];
    if (do_relu) v = fmaxf(v, 0.f);
    out[(size_t)n * D + colOff + l] = v;
  }
}

// ---- launch ---------------------------------------------------------------

extern "C" void kernel_launch(void* const* d_in, const int* in_sizes, int n_in,
                              void* d_out, int out_size, void* d_ws, size_t ws_size,
                              hipStream_t stream) {
  const float* x  = (const float*)d_in[0];
  const int* edge = (const int*)d_in[1];
  const float* W1 = (const float*)d_in[2];
  const float* b1 = (const float*)d_in[3];
  const float* W2 = (const float*)d_in[4];
  const float* b2 = (const float*)d_in[5];
  const int N = in_sizes[0] / D;   // 50000
  const int E = in_sizes[1] / 2;   // 1.6M
  const int* srcp = edge;
  const int* dstp = edge + E;
  float* out = (float*)d_out;

  auto align = [](size_t v) { return (v + 255) & ~(size_t)255; };
  char* ws = (char*)d_ws;
  size_t o = 0;
  int*   deg     = (int*)(ws + o);   o += align((size_t)N * 4);
  float* dinv    = (float*)(ws + o); o += align((size_t)N * 4);
  int*   offsets = (int*)(ws + o);   o += align((size_t)(N + 1) * 4);
  int*   cursor  = (int*)(ws + o);   o += align((size_t)N * 4);
  int2*  csr     = (int2*)(ws + o);  o += align((size_t)E * 8);
  float* H4      = (float*)(ws + o); o += align((size_t)N * D * 4);

  // CSR build
  hipMemsetAsync(deg, 0, (size_t)N * 4, stream);
  deg_kernel<<<(E + 255) / 256, 256, 0, stream>>>(dstp, deg, E);
  scan_kernel<<<1, 1024, 0, stream>>>(deg, offsets, cursor, dinv, N);
  place_kernel<<<(E + 255) / 256, 256, 0, stream>>>(srcp, dstp, dinv, cursor, csr, E);

  int gemm_blocks = (N + 31) / 32;
  int agg_blocks = (N + 3) / 4;

  // layer 1: h1 = relu(A @ (x@W1) + b1) -> d_out (scratch)
  gemm_kernel<<<gemm_blocks, 256, 0, stream>>>(x, W1, H4, N);
  for (int p = 0; p < NSPLIT; ++p)
    agg32_kernel<<<agg_blocks, 256, 0, stream>>>(H4 + (size_t)p * N * SPLITW, offsets, csr,
                                                 dinv, b1, out, N, p * SPLITW, 1);

  // layer 2: z = A @ (h1@W2) + b2 -> d_out
  gemm_kernel<<<gemm_blocks, 256, 0, stream>>>(out, W2, H4, N);
  for (int p = 0; p < NSPLIT; ++p)
    agg32_kernel<<<agg_blocks, 256, 0, stream>>>(H4 + (size_t)p * N * SPLITW, offsets, csr,
                                                 dinv, b2, out, N, p * SPLITW, 0);
}

// Round 4
// 439.981 us; speedup vs baseline: 1.7437x; 1.7437x over previous
//
#include <hip/hip_runtime.h>

#define D 128

// ---- degree histogram -----------------------------------------------------

__global__ __launch_bounds__(256) void deg_kernel(const int* __restrict__ dst,
                                                  int* __restrict__ deg, int E) {
  int e = blockIdx.x * 256 + threadIdx.x;
  if (e < E) atomicAdd(&deg[dst[e]], 1);
}

// ---- parallel scan, stage 1: per-block (1024-elem chunk) sums -------------

__global__ __launch_bounds__(256) void bsum_kernel(const int* __restrict__ deg,
                                                   int* __restrict__ bsum) {
  __shared__ int ws[4];
  int i0 = blockIdx.x * 1024 + threadIdx.x * 4;
  int4 v = *reinterpret_cast<const int4*>(deg + i0);   // deg zero-padded to 1024 mult
  int s = v.x + v.y + v.z + v.w;
  #pragma unroll
  for (int off = 32; off; off >>= 1) s += __shfl_down(s, off);
  if ((threadIdx.x & 63) == 0) ws[threadIdx.x >> 6] = s;
  __syncthreads();
  if (threadIdx.x == 0) bsum[blockIdx.x] = ws[0] + ws[1] + ws[2] + ws[3];
}

// ---- parallel scan, stage 2: offsets/cursor/dinv --------------------------

__global__ __launch_bounds__(256) void scan_kernel(const int* __restrict__ deg,
                                                   const int* __restrict__ bsum,
                                                   int* __restrict__ offsets,
                                                   int* __restrict__ cursor,
                                                   float* __restrict__ dinv,
                                                   int N, int E) {
  __shared__ int ts[256];
  int b = blockIdx.x;
  int base = 0;
  for (int t = 0; t < b; ++t) base += bsum[t];       // <=48 uniform scalar loads

  int i0 = b * 1024 + threadIdx.x * 4;
  int4 v = *reinterpret_cast<const int4*>(deg + i0); // zero-padded
  int t4 = v.x + v.y + v.z + v.w;
  ts[threadIdx.x] = t4;
  __syncthreads();
  #pragma unroll
  for (int off = 1; off < 256; off <<= 1) {
    int u = (threadIdx.x >= off) ? ts[threadIdx.x - off] : 0;
    __syncthreads();
    ts[threadIdx.x] += u;
    __syncthreads();
  }
  int run = base + ts[threadIdx.x] - t4;             // exclusive prefix

  int dd[4] = {v.x, v.y, v.z, v.w};
  #pragma unroll
  for (int k = 0; k < 4; ++k) {
    int i = i0 + k;
    if (i < N) {
      offsets[i] = run;
      cursor[i] = run;
      dinv[i] = rsqrtf(1.0f + (float)dd[k]);
    }
    run += dd[k];
  }
  if (b == 0 && threadIdx.x == 0) offsets[N] = E;
}

// ---- counting-sort edges into CSR buckets, pack {src, norm} --------------

__global__ __launch_bounds__(256) void place_kernel(const int* __restrict__ src,
                                                    const int* __restrict__ dst,
                                                    const float* __restrict__ dinv,
                                                    int* __restrict__ cursor,
                                                    int2* __restrict__ csr, int E) {
  int e = blockIdx.x * 256 + threadIdx.x;
  if (e >= E) return;
  int s = src[e];
  int d = dst[e];
  int pos = atomicAdd(&cursor[d], 1);
  int2 p;
  p.x = s;
  p.y = __float_as_int(dinv[s] * dinv[d]);
  csr[pos] = p;
}

// ---- GEMM: H[N,128] = X[N,128] @ W[128,128] ------------------------------
// 256 thr/block = 4 waves, 32 rows/block; wave-uniform LDS reads (broadcast).

__global__ __launch_bounds__(256) void gemm_kernel(const float* __restrict__ X,
                                                   const float* __restrict__ W,
                                                   float* __restrict__ H, int N) {
  __shared__ float xs[32 * D];
  int row0 = blockIdx.x * 32;
  #pragma unroll
  for (int jj = 0; jj < 4; ++jj) {
    int f4 = threadIdx.x + jj * 256;
    int r = f4 >> 5;
    float4 v = make_float4(0.f, 0.f, 0.f, 0.f);
    if (row0 + r < N) v = *reinterpret_cast<const float4*>(X + (size_t)row0 * D + (size_t)f4 * 4);
    *reinterpret_cast<float4*>(xs + f4 * 4) = v;
  }
  __syncthreads();

  int tx = threadIdx.x & 63;
  int ty = threadIdx.x >> 6;          // wave id -> rows ty*8..ty*8+7
  int c0 = tx * 2;
  float2 acc[8];
  #pragma unroll
  for (int r = 0; r < 8; ++r) acc[r] = make_float2(0.f, 0.f);
  const float* xbase = xs + ty * 8 * D;

  for (int k = 0; k < D; k += 4) {
    float2 w0 = *reinterpret_cast<const float2*>(W + (size_t)(k + 0) * D + c0);
    float2 w1 = *reinterpret_cast<const float2*>(W + (size_t)(k + 1) * D + c0);
    float2 w2 = *reinterpret_cast<const float2*>(W + (size_t)(k + 2) * D + c0);
    float2 w3 = *reinterpret_cast<const float2*>(W + (size_t)(k + 3) * D + c0);
    #pragma unroll
    for (int r = 0; r < 8; ++r) {
      float4 xv = *reinterpret_cast<const float4*>(xbase + r * D + k);
      acc[r].x = fmaf(xv.x, w0.x, acc[r].x); acc[r].y = fmaf(xv.x, w0.y, acc[r].y);
      acc[r].x = fmaf(xv.y, w1.x, acc[r].x); acc[r].y = fmaf(xv.y, w1.y, acc[r].y);
      acc[r].x = fmaf(xv.z, w2.x, acc[r].x); acc[r].y = fmaf(xv.z, w2.y, acc[r].y);
      acc[r].x = fmaf(xv.w, w3.x, acc[r].x); acc[r].y = fmaf(xv.w, w3.y, acc[r].y);
    }
  }

  #pragma unroll
  for (int r = 0; r < 8; ++r) {
    int row = row0 + ty * 8 + r;
    if (row < N) *reinterpret_cast<float2*>(H + (size_t)row * D + c0) = acc[r];
  }
}

// ---- Aggregation: one wave per dst node, fused epilogue ------------------
// Lane layout: g = lane>>5 (edge group), l = lane&31 (feature quad).
// Group g handles edges beg+g, beg+g+2, ... (unroll 2 -> 4 gathers in flight)

__global__ __launch_bounds__(256) void agg_kernel(const float* __restrict__ H,
                                                  const int* __restrict__ offsets,
                                                  const int2* __restrict__ csr,
                                                  const float* __restrict__ dinv,
                                                  const float* __restrict__ bias,
                                                  float* __restrict__ out,
                                                  int N, int do_relu) {
  int n = blockIdx.x * 4 + (threadIdx.x >> 6);
  int lane = threadIdx.x & 63;
  int g = lane >> 5;
  int l = lane & 31;
  if (n >= N) return;
  int beg = offsets[n];
  int end = offsets[n + 1];

  float4 acc = make_float4(0.f, 0.f, 0.f, 0.f);
  int j = beg + g;
  for (; j + 2 < end; j += 4) {
    int2 p0 = csr[j];
    int2 p1 = csr[j + 2];
    float4 h0 = *reinterpret_cast<const float4*>(H + (size_t)p0.x * D + l * 4);
    float4 h1 = *reinterpret_cast<const float4*>(H + (size_t)p1.x * D + l * 4);
    float m0 = __int_as_float(p0.y);
    float m1 = __int_as_float(p1.y);
    acc.x = fmaf(h0.x, m0, acc.x); acc.y = fmaf(h0.y, m0, acc.y);
    acc.z = fmaf(h0.z, m0, acc.z); acc.w = fmaf(h0.w, m0, acc.w);
    acc.x = fmaf(h1.x, m1, acc.x); acc.y = fmaf(h1.y, m1, acc.y);
    acc.z = fmaf(h1.z, m1, acc.z); acc.w = fmaf(h1.w, m1, acc.w);
  }
  if (j < end) {
    int2 p0 = csr[j];
    float m0 = __int_as_float(p0.y);
    float4 h0 = *reinterpret_cast<const float4*>(H + (size_t)p0.x * D + l * 4);
    acc.x = fmaf(h0.x, m0, acc.x); acc.y = fmaf(h0.y, m0, acc.y);
    acc.z = fmaf(h0.z, m0, acc.z); acc.w = fmaf(h0.w, m0, acc.w);
  }

  acc.x += __shfl_xor(acc.x, 32);
  acc.y += __shfl_xor(acc.y, 32);
  acc.z += __shfl_xor(acc.z, 32);
  acc.w += __shfl_xor(acc.w, 32);

  if (g == 0) {
    float di = dinv[n];
    float dii = di * di;
    float4 hs = *reinterpret_cast<const float4*>(H + (size_t)n * D + l * 4);
    float4 bv = *reinterpret_cast<const float4*>(bias + l * 4);
    float4 v;
    v.x = fmaf(hs.x, dii, acc.x) + bv.x;
    v.y = fmaf(hs.y, dii, acc.y) + bv.y;
    v.z = fmaf(hs.z, dii, acc.z) + bv.z;
    v.w = fmaf(hs.w, dii, acc.w) + bv.w;
    if (do_relu) {
      v.x = fmaxf(v.x, 0.f); v.y = fmaxf(v.y, 0.f);
      v.z = fmaxf(v.z, 0.f); v.w = fmaxf(v.w, 0.f);
    }
    *reinterpret_cast<float4*>(out + (size_t)n * D + l * 4) = v;
  }
}

// ---- launch ---------------------------------------------------------------

extern "C" void kernel_launch(void* const* d_in, const int* in_sizes, int n_in,
                              void* d_out, int out_size, void* d_ws, size_t ws_size,
                              hipStream_t stream) {
  const float* x  = (const float*)d_in[0];
  const int* edge = (const int*)d_in[1];
  const float* W1 = (const float*)d_in[2];
  const float* b1 = (const float*)d_in[3];
  const float* W2 = (const float*)d_in[4];
  const float* b2 = (const float*)d_in[5];
  const int N = in_sizes[0] / D;   // 50000
  const int E = in_sizes[1] / 2;   // 1.6M
  const int* srcp = edge;
  const int* dstp = edge + E;
  float* out = (float*)d_out;

  const int NP = (N + 1023) & ~1023;        // zero-padded degree count
  const int SB = NP / 1024;                 // scan blocks

  auto align = [](size_t v) { return (v + 255) & ~(size_t)255; };
  char* ws = (char*)d_ws;
  size_t o = 0;
  int*   deg     = (int*)(ws + o);   o += align((size_t)NP * 4);
  int*   bsum    = (int*)(ws + o);   o += align((size_t)SB * 4);
  float* dinv    = (float*)(ws + o); o += align((size_t)N * 4);
  int*   offsets = (int*)(ws + o);   o += align((size_t)(N + 1) * 4);
  int*   cursor  = (int*)(ws + o);   o += align((size_t)N * 4);
  int2*  csr     = (int2*)(ws + o);  o += align((size_t)E * 8);
  float* bufH    = (float*)(ws + o); o += align((size_t)N * D * 4);

  // CSR build
  hipMemsetAsync(deg, 0, (size_t)NP * 4, stream);
  deg_kernel<<<(E + 255) / 256, 256, 0, stream>>>(dstp, deg, E);
  bsum_kernel<<<SB, 256, 0, stream>>>(deg, bsum);
  scan_kernel<<<SB, 256, 0, stream>>>(deg, bsum, offsets, cursor, dinv, N, E);
  place_kernel<<<(E + 255) / 256, 256, 0, stream>>>(srcp, dstp, dinv, cursor, csr, E);

  int gemm_blocks = (N + 31) / 32;
  int agg_blocks = (N + 3) / 4;

  // layer 1: h1 = relu(A @ (x@W1) + b1) -> d_out (scratch)
  gemm_kernel<<<gemm_blocks, 256, 0, stream>>>(x, W1, bufH, N);
  agg_kernel<<<agg_blocks, 256, 0, stream>>>(bufH, offsets, csr, dinv, b1, out, N, 1);

  // layer 2: z = A @ (h1@W2) + b2 -> d_out
  gemm_kernel<<<gemm_blocks, 256, 0, stream>>>(out, W2, bufH, N);
  agg_kernel<<<agg_blocks, 256, 0, stream>>>(bufH, offsets, csr, dinv, b2, out, N, 0);
}

// Round 5
// 402.639 us; speedup vs baseline: 1.9054x; 1.0927x over previous
//
#include <hip/hip_runtime.h>

#define D 128
#define NCH 7          // src chunks: src>>13 -> 0..6 (8192 nodes = 4MB of H per chunk)
#define CSH 13

// ---- bucketed degree histogram + per-edge rank ----------------------------

__global__ __launch_bounds__(256) void deg2_kernel(const int* __restrict__ src,
                                                   const int* __restrict__ dst,
                                                   int* __restrict__ deg2,
                                                   int* __restrict__ rank, int E) {
  int e = blockIdx.x * 256 + threadIdx.x;
  if (e >= E) return;
  int b = dst[e] * NCH + (src[e] >> CSH);
  rank[e] = atomicAdd(&deg2[b], 1);
}

// ---- parallel scan stage 1: per-1024-chunk sums ---------------------------

__global__ __launch_bounds__(256) void bsum_kernel(const int* __restrict__ deg2,
                                                   int* __restrict__ bsum) {
  __shared__ int ws[4];
  int i0 = blockIdx.x * 1024 + threadIdx.x * 4;
  int4 v = *reinterpret_cast<const int4*>(deg2 + i0);   // zero-padded
  int s = v.x + v.y + v.z + v.w;
  #pragma unroll
  for (int off = 32; off; off >>= 1) s += __shfl_down(s, off);
  if ((threadIdx.x & 63) == 0) ws[threadIdx.x >> 6] = s;
  __syncthreads();
  if (threadIdx.x == 0) bsum[blockIdx.x] = ws[0] + ws[1] + ws[2] + ws[3];
}

// ---- parallel scan stage 2: exclusive offsets -----------------------------

__global__ __launch_bounds__(256) void scan2_kernel(const int* __restrict__ deg2,
                                                    const int* __restrict__ bsum,
                                                    int* __restrict__ offsets,
                                                    int M, int E) {
  __shared__ int ts[256];
  int b = blockIdx.x;
  int base = 0;
  for (int t = 0; t < b; ++t) base += bsum[t];

  int i0 = b * 1024 + threadIdx.x * 4;
  int4 v = *reinterpret_cast<const int4*>(deg2 + i0);
  int t4 = v.x + v.y + v.z + v.w;
  ts[threadIdx.x] = t4;
  __syncthreads();
  #pragma unroll
  for (int off = 1; off < 256; off <<= 1) {
    int u = (threadIdx.x >= off) ? ts[threadIdx.x - off] : 0;
    __syncthreads();
    ts[threadIdx.x] += u;
    __syncthreads();
  }
  int run = base + ts[threadIdx.x] - t4;

  int dd[4] = {v.x, v.y, v.z, v.w};
  #pragma unroll
  for (int k = 0; k < 4; ++k) {
    int i = i0 + k;
    if (i < M) offsets[i] = run;
    run += dd[k];
  }
  if (b == 0 && threadIdx.x == 0) offsets[M] = E;
}

// ---- dinv from chunked offsets --------------------------------------------

__global__ __launch_bounds__(256) void dinv_kernel(const int* __restrict__ offsets,
                                                   float* __restrict__ dinv, int N) {
  int n = blockIdx.x * 256 + threadIdx.x;
  if (n >= N) return;
  int dg = offsets[(n + 1) * NCH] - offsets[n * NCH];
  dinv[n] = rsqrtf(1.0f + (float)dg);
}

// ---- atomic-free placement ------------------------------------------------

__global__ __launch_bounds__(256) void place_kernel(const int* __restrict__ src,
                                                    const int* __restrict__ dst,
                                                    const int* __restrict__ rank,
                                                    const int* __restrict__ offsets,
                                                    const float* __restrict__ dinv,
                                                    int2* __restrict__ csr, int E) {
  int e = blockIdx.x * 256 + threadIdx.x;
  if (e >= E) return;
  int s = src[e];
  int d = dst[e];
  int pos = offsets[d * NCH + (s >> CSH)] + rank[e];
  int2 p;
  p.x = s;
  p.y = __float_as_int(dinv[s] * dinv[d]);
  csr[pos] = p;
}

// ---- GEMM: H[N,128] = X[N,128] @ W[128,128] ------------------------------

__global__ __launch_bounds__(256) void gemm_kernel(const float* __restrict__ X,
                                                   const float* __restrict__ W,
                                                   float* __restrict__ H, int N) {
  __shared__ float xs[32 * D];
  int row0 = blockIdx.x * 32;
  #pragma unroll
  for (int jj = 0; jj < 4; ++jj) {
    int f4 = threadIdx.x + jj * 256;
    int r = f4 >> 5;
    float4 v = make_float4(0.f, 0.f, 0.f, 0.f);
    if (row0 + r < N) v = *reinterpret_cast<const float4*>(X + (size_t)row0 * D + (size_t)f4 * 4);
    *reinterpret_cast<float4*>(xs + f4 * 4) = v;
  }
  __syncthreads();

  int tx = threadIdx.x & 63;
  int ty = threadIdx.x >> 6;
  int c0 = tx * 2;
  float2 acc[8];
  #pragma unroll
  for (int r = 0; r < 8; ++r) acc[r] = make_float2(0.f, 0.f);
  const float* xbase = xs + ty * 8 * D;

  for (int k = 0; k < D; k += 4) {
    float2 w0 = *reinterpret_cast<const float2*>(W + (size_t)(k + 0) * D + c0);
    float2 w1 = *reinterpret_cast<const float2*>(W + (size_t)(k + 1) * D + c0);
    float2 w2 = *reinterpret_cast<const float2*>(W + (size_t)(k + 2) * D + c0);
    float2 w3 = *reinterpret_cast<const float2*>(W + (size_t)(k + 3) * D + c0);
    #pragma unroll
    for (int r = 0; r < 8; ++r) {
      float4 xv = *reinterpret_cast<const float4*>(xbase + r * D + k);
      acc[r].x = fmaf(xv.x, w0.x, acc[r].x); acc[r].y = fmaf(xv.x, w0.y, acc[r].y);
      acc[r].x = fmaf(xv.y, w1.x, acc[r].x); acc[r].y = fmaf(xv.y, w1.y, acc[r].y);
      acc[r].x = fmaf(xv.z, w2.x, acc[r].x); acc[r].y = fmaf(xv.z, w2.y, acc[r].y);
      acc[r].x = fmaf(xv.w, w3.x, acc[r].x); acc[r].y = fmaf(xv.w, w3.y, acc[r].y);
    }
  }

  #pragma unroll
  for (int r = 0; r < 8; ++r) {
    int row = row0 + ty * 8 + r;
    if (row < N) *reinterpret_cast<float2*>(H + (size_t)row * D + c0) = acc[r];
  }
}

// ---- Aggregation: one wave per dst node, looping src chunks ---------------
// g = lane>>5 edge-group (interleaved within chunk), l = lane&31 feature quad.

__global__ __launch_bounds__(256) void agg_kernel(const float* __restrict__ H,
                                                  const int* __restrict__ offsets,
                                                  const int2* __restrict__ csr,
                                                  const float* __restrict__ dinv,
                                                  const float* __restrict__ bias,
                                                  float* __restrict__ out,
                                                  int N, int do_relu) {
  int n = blockIdx.x * 4 + (threadIdx.x >> 6);
  int lane = threadIdx.x & 63;
  int g = lane >> 5;
  int l = lane & 31;
  if (n >= N) return;

  int bnd[NCH + 1];
  #pragma unroll
  for (int c = 0; c <= NCH; ++c) bnd[c] = offsets[n * NCH + c];

  float4 acc = make_float4(0.f, 0.f, 0.f, 0.f);
  #pragma unroll 1
  for (int c = 0; c < NCH; ++c) {
    int end = bnd[c + 1];
    int j = bnd[c] + g;
    for (; j + 2 < end; j += 4) {
      int2 p0 = csr[j];
      int2 p1 = csr[j + 2];
      float4 h0 = *reinterpret_cast<const float4*>(H + (size_t)p0.x * D + l * 4);
      float4 h1 = *reinterpret_cast<const float4*>(H + (size_t)p1.x * D + l * 4);
      float m0 = __int_as_float(p0.y);
      float m1 = __int_as_float(p1.y);
      acc.x = fmaf(h0.x, m0, acc.x); acc.y = fmaf(h0.y, m0, acc.y);
      acc.z = fmaf(h0.z, m0, acc.z); acc.w = fmaf(h0.w, m0, acc.w);
      acc.x = fmaf(h1.x, m1, acc.x); acc.y = fmaf(h1.y, m1, acc.y);
      acc.z = fmaf(h1.z, m1, acc.z); acc.w = fmaf(h1.w, m1, acc.w);
    }
    if (j < end) {
      int2 p0 = csr[j];
      float m0 = __int_as_float(p0.y);
      float4 h0 = *reinterpret_cast<const float4*>(H + (size_t)p0.x * D + l * 4);
      acc.x = fmaf(h0.x, m0, acc.x); acc.y = fmaf(h0.y, m0, acc.y);
      acc.z = fmaf(h0.z, m0, acc.z); acc.w = fmaf(h0.w, m0, acc.w);
    }
  }

  acc.x += __shfl_xor(acc.x, 32);
  acc.y += __shfl_xor(acc.y, 32);
  acc.z += __shfl_xor(acc.z, 32);
  acc.w += __shfl_xor(acc.w, 32);

  if (g == 0) {
    float di = dinv[n];
    float dii = di * di;
    float4 hs = *reinterpret_cast<const float4*>(H + (size_t)n * D + l * 4);
    float4 bv = *reinterpret_cast<const float4*>(bias + l * 4);
    float4 v;
    v.x = fmaf(hs.x, dii, acc.x) + bv.x;
    v.y = fmaf(hs.y, dii, acc.y) + bv.y;
    v.z = fmaf(hs.z, dii, acc.z) + bv.z;
    v.w = fmaf(hs.w, dii, acc.w) + bv.w;
    if (do_relu) {
      v.x = fmaxf(v.x, 0.f); v.y = fmaxf(v.y, 0.f);
      v.z = fmaxf(v.z, 0.f); v.w = fmaxf(v.w, 0.f);
    }
    *reinterpret_cast<float4*>(out + (size_t)n * D + l * 4) = v;
  }
}

// ---- launch ---------------------------------------------------------------

extern "C" void kernel_launch(void* const* d_in, const int* in_sizes, int n_in,
                              void* d_out, int out_size, void* d_ws, size_t ws_size,
                              hipStream_t stream) {
  const float* x  = (const float*)d_in[0];
  const int* edge = (const int*)d_in[1];
  const float* W1 = (const float*)d_in[2];
  const float* b1 = (const float*)d_in[3];
  const float* W2 = (const float*)d_in[4];
  const float* b2 = (const float*)d_in[5];
  const int N = in_sizes[0] / D;   // 50000
  const int E = in_sizes[1] / 2;   // 1.6M
  const int* srcp = edge;
  const int* dstp = edge + E;
  float* out = (float*)d_out;

  const int M  = N * NCH;                   // bucket count
  const int MP = (M + 1023) & ~1023;        // padded for scan
  const int SB = MP / 1024;

  auto align = [](size_t v) { return (v + 255) & ~(size_t)255; };
  char* ws = (char*)d_ws;
  size_t o = 0;
  int*   deg2    = (int*)(ws + o);   o += align((size_t)MP * 4);
  int*   bsum    = (int*)(ws + o);   o += align((size_t)SB * 4);
  int*   offsets = (int*)(ws + o);   o += align((size_t)(M + 1) * 4);
  int*   rank    = (int*)(ws + o);   o += align((size_t)E * 4);
  float* dinv    = (float*)(ws + o); o += align((size_t)N * 4);
  int2*  csr     = (int2*)(ws + o);  o += align((size_t)E * 8);
  float* bufH    = (float*)(ws + o); o += align((size_t)N * D * 4);

  // CSR build (chunked by src>>13)
  hipMemsetAsync(deg2, 0, (size_t)MP * 4, stream);
  deg2_kernel<<<(E + 255) / 256, 256, 0, stream>>>(srcp, dstp, deg2, rank, E);
  bsum_kernel<<<SB, 256, 0, stream>>>(deg2, bsum);
  scan2_kernel<<<SB, 256, 0, stream>>>(deg2, bsum, offsets, M, E);
  dinv_kernel<<<(N + 255) / 256, 256, 0, stream>>>(offsets, dinv, N);
  place_kernel<<<(E + 255) / 256, 256, 0, stream>>>(srcp, dstp, rank, offsets, dinv, csr, E);

  int gemm_blocks = (N + 31) / 32;
  int agg_blocks = (N + 3) / 4;

  // layer 1: h1 = relu(A @ (x@W1) + b1) -> d_out (scratch)
  gemm_kernel<<<gemm_blocks, 256, 0, stream>>>(x, W1, bufH, N);
  agg_kernel<<<agg_blocks, 256, 0, stream>>>(bufH, offsets, csr, dinv, b1, out, N, 1);

  // layer 2: z = A @ (h1@W2) + b2 -> d_out
  gemm_kernel<<<gemm_blocks, 256, 0, stream>>>(out, W2, bufH, N);
  agg_kernel<<<agg_blocks, 256, 0, stream>>>(bufH, offsets, csr, dinv, b2, out, N, 0);
}

// Round 6
// 317.102 us; speedup vs baseline: 2.4193x; 1.2697x over previous
//
#include <hip/hip_runtime.h>
#include <hip/hip_fp16.h>
#include <type_traits>

#define D 128
#define NCH 4          // src chunks: src>>14 -> 0..3 (16384 nodes * 256B = 4MB fp16 H per chunk)
#define CSH 14

// ---- bucketed degree histogram + per-edge rank ----------------------------

__global__ __launch_bounds__(256) void deg2_kernel(const int* __restrict__ src,
                                                   const int* __restrict__ dst,
                                                   int* __restrict__ deg2,
                                                   int* __restrict__ rank, int E) {
  int e = blockIdx.x * 256 + threadIdx.x;
  if (e >= E) return;
  int b = dst[e] * NCH + (src[e] >> CSH);
  rank[e] = atomicAdd(&deg2[b], 1);
}

// ---- parallel scan stage 1: per-1024-chunk sums ---------------------------

__global__ __launch_bounds__(256) void bsum_kernel(const int* __restrict__ deg2,
                                                   int* __restrict__ bsum) {
  __shared__ int ws[4];
  int i0 = blockIdx.x * 1024 + threadIdx.x * 4;
  int4 v = *reinterpret_cast<const int4*>(deg2 + i0);   // zero-padded
  int s = v.x + v.y + v.z + v.w;
  #pragma unroll
  for (int off = 32; off; off >>= 1) s += __shfl_down(s, off);
  if ((threadIdx.x & 63) == 0) ws[threadIdx.x >> 6] = s;
  __syncthreads();
  if (threadIdx.x == 0) bsum[blockIdx.x] = ws[0] + ws[1] + ws[2] + ws[3];
}

// ---- parallel scan stage 2: exclusive offsets -----------------------------

__global__ __launch_bounds__(256) void scan2_kernel(const int* __restrict__ deg2,
                                                    const int* __restrict__ bsum,
                                                    int* __restrict__ offsets,
                                                    int M, int E) {
  __shared__ int ts[256];
  int b = blockIdx.x;
  int base = 0;
  for (int t = 0; t < b; ++t) base += bsum[t];

  int i0 = b * 1024 + threadIdx.x * 4;
  int4 v = *reinterpret_cast<const int4*>(deg2 + i0);
  int t4 = v.x + v.y + v.z + v.w;
  ts[threadIdx.x] = t4;
  __syncthreads();
  #pragma unroll
  for (int off = 1; off < 256; off <<= 1) {
    int u = (threadIdx.x >= off) ? ts[threadIdx.x - off] : 0;
    __syncthreads();
    ts[threadIdx.x] += u;
    __syncthreads();
  }
  int run = base + ts[threadIdx.x] - t4;

  int dd[4] = {v.x, v.y, v.z, v.w};
  #pragma unroll
  for (int k = 0; k < 4; ++k) {
    int i = i0 + k;
    if (i < M) offsets[i] = run;
    run += dd[k];
  }
  if (b == 0 && threadIdx.x == 0) offsets[M] = E;
}

// ---- dinv from chunked offsets --------------------------------------------

__global__ __launch_bounds__(256) void dinv_kernel(const int* __restrict__ offsets,
                                                   float* __restrict__ dinv, int N) {
  int n = blockIdx.x * 256 + threadIdx.x;
  if (n >= N) return;
  int dg = offsets[(n + 1) * NCH] - offsets[n * NCH];
  dinv[n] = rsqrtf(1.0f + (float)dg);
}

// ---- atomic-free placement; pack {src:17, norm_q15:15} into 4 B ----------

__global__ __launch_bounds__(256) void place_kernel(const int* __restrict__ src,
                                                    const int* __restrict__ dst,
                                                    const int* __restrict__ rank,
                                                    const int* __restrict__ offsets,
                                                    const float* __restrict__ dinv,
                                                    unsigned int* __restrict__ csr, int E) {
  int e = blockIdx.x * 256 + threadIdx.x;
  if (e >= E) return;
  int s = src[e];
  int d = dst[e];
  int pos = offsets[d * NCH + (s >> CSH)] + rank[e];
  float nm = dinv[s] * dinv[d];                         // in (0, 1]
  unsigned int q = (unsigned int)__float2int_rn(nm * 32767.0f);
  csr[pos] = ((unsigned int)s << 15) | q;
}

// ---- GEMM: H[N,128](fp16) = X[N,128] @ W[128,128] -------------------------
// X staged f32 in LDS (converted on load if fp16); wave-uniform LDS broadcasts.

template <typename TI>
__global__ __launch_bounds__(256) void gemm_kernel(const TI* __restrict__ X,
                                                   const float* __restrict__ W,
                                                   __half* __restrict__ H, int N) {
  __shared__ float xs[32 * D];
  int row0 = blockIdx.x * 32;
  if constexpr (std::is_same<TI, float>::value) {
    #pragma unroll
    for (int jj = 0; jj < 4; ++jj) {
      int f4 = threadIdx.x + jj * 256;
      int r = f4 >> 5;
      float4 v = make_float4(0.f, 0.f, 0.f, 0.f);
      if (row0 + r < N) v = *reinterpret_cast<const float4*>(X + (size_t)row0 * D + (size_t)f4 * 4);
      *reinterpret_cast<float4*>(xs + f4 * 4) = v;
    }
  } else {
    #pragma unroll
    for (int jj = 0; jj < 2; ++jj) {
      int g8 = threadIdx.x + jj * 256;     // 8-half group, 512 groups
      int r = g8 >> 4;                     // 16 groups per row
      uint4 raw = make_uint4(0u, 0u, 0u, 0u);
      if (row0 + r < N)
        raw = *reinterpret_cast<const uint4*>((const __half*)X + (size_t)row0 * D + (size_t)g8 * 8);
      const __half2* hp = reinterpret_cast<const __half2*>(&raw);
      float* dst8 = xs + (size_t)g8 * 8;
      #pragma unroll
      for (int k = 0; k < 4; ++k) {
        float2 f = __half22float2(hp[k]);
        dst8[k * 2] = f.x;
        dst8[k * 2 + 1] = f.y;
      }
    }
  }
  __syncthreads();

  int tx = threadIdx.x & 63;
  int ty = threadIdx.x >> 6;
  int c0 = tx * 2;
  float2 acc[8];
  #pragma unroll
  for (int r = 0; r < 8; ++r) acc[r] = make_float2(0.f, 0.f);
  const float* xbase = xs + ty * 8 * D;

  for (int k = 0; k < D; k += 4) {
    float2 w0 = *reinterpret_cast<const float2*>(W + (size_t)(k + 0) * D + c0);
    float2 w1 = *reinterpret_cast<const float2*>(W + (size_t)(k + 1) * D + c0);
    float2 w2 = *reinterpret_cast<const float2*>(W + (size_t)(k + 2) * D + c0);
    float2 w3 = *reinterpret_cast<const float2*>(W + (size_t)(k + 3) * D + c0);
    #pragma unroll
    for (int r = 0; r < 8; ++r) {
      float4 xv = *reinterpret_cast<const float4*>(xbase + r * D + k);
      acc[r].x = fmaf(xv.x, w0.x, acc[r].x); acc[r].y = fmaf(xv.x, w0.y, acc[r].y);
      acc[r].x = fmaf(xv.y, w1.x, acc[r].x); acc[r].y = fmaf(xv.y, w1.y, acc[r].y);
      acc[r].x = fmaf(xv.z, w2.x, acc[r].x); acc[r].y = fmaf(xv.z, w2.y, acc[r].y);
      acc[r].x = fmaf(xv.w, w3.x, acc[r].x); acc[r].y = fmaf(xv.w, w3.y, acc[r].y);
    }
  }

  #pragma unroll
  for (int r = 0; r < 8; ++r) {
    int row = row0 + ty * 8 + r;
    if (row < N)
      *reinterpret_cast<__half2*>(H + (size_t)row * D + c0) = __floats2half2_rn(acc[r].x, acc[r].y);
  }
}

// ---- Aggregation: one wave per dst node, fp16 gathers, fused epilogue -----

template <int DO_RELU, typename TO>
__global__ __launch_bounds__(256) void agg_kernel(const __half* __restrict__ H,
                                                  const int* __restrict__ offsets,
                                                  const unsigned int* __restrict__ csr,
                                                  const float* __restrict__ dinv,
                                                  const float* __restrict__ bias,
                                                  TO* __restrict__ out, int N) {
  int n = blockIdx.x * 4 + (threadIdx.x >> 6);
  int lane = threadIdx.x & 63;
  int g = lane >> 5;
  int l = lane & 31;
  if (n >= N) return;

  int bnd[NCH + 1];
  #pragma unroll
  for (int c = 0; c <= NCH; ++c) bnd[c] = offsets[n * NCH + c];

  float4 acc = make_float4(0.f, 0.f, 0.f, 0.f);
  #pragma unroll 1
  for (int c = 0; c < NCH; ++c) {
    int end = bnd[c + 1];
    int j = bnd[c] + g;
    for (; j + 2 < end; j += 4) {
      unsigned int p0 = csr[j];
      unsigned int p1 = csr[j + 2];
      float m0 = (float)(p0 & 0x7fffu) * (1.0f / 32767.0f);
      float m1 = (float)(p1 & 0x7fffu) * (1.0f / 32767.0f);
      uint2 r0 = *reinterpret_cast<const uint2*>(H + (size_t)(p0 >> 15) * D + l * 4);
      uint2 r1 = *reinterpret_cast<const uint2*>(H + (size_t)(p1 >> 15) * D + l * 4);
      const __half2* h0 = reinterpret_cast<const __half2*>(&r0);
      const __half2* h1 = reinterpret_cast<const __half2*>(&r1);
      float2 a0 = __half22float2(h0[0]), b0 = __half22float2(h0[1]);
      float2 a1 = __half22float2(h1[0]), b1 = __half22float2(h1[1]);
      acc.x = fmaf(a0.x, m0, acc.x); acc.y = fmaf(a0.y, m0, acc.y);
      acc.z = fmaf(b0.x, m0, acc.z); acc.w = fmaf(b0.y, m0, acc.w);
      acc.x = fmaf(a1.x, m1, acc.x); acc.y = fmaf(a1.y, m1, acc.y);
      acc.z = fmaf(b1.x, m1, acc.z); acc.w = fmaf(b1.y, m1, acc.w);
    }
    if (j < end) {
      unsigned int p0 = csr[j];
      float m0 = (float)(p0 & 0x7fffu) * (1.0f / 32767.0f);
      uint2 r0 = *reinterpret_cast<const uint2*>(H + (size_t)(p0 >> 15) * D + l * 4);
      const __half2* h0 = reinterpret_cast<const __half2*>(&r0);
      float2 a0 = __half22float2(h0[0]), b0 = __half22float2(h0[1]);
      acc.x = fmaf(a0.x, m0, acc.x); acc.y = fmaf(a0.y, m0, acc.y);
      acc.z = fmaf(b0.x, m0, acc.z); acc.w = fmaf(b0.y, m0, acc.w);
    }
  }

  acc.x += __shfl_xor(acc.x, 32);
  acc.y += __shfl_xor(acc.y, 32);
  acc.z += __shfl_xor(acc.z, 32);
  acc.w += __shfl_xor(acc.w, 32);

  if (g == 0) {
    float di = dinv[n];
    float dii = di * di;
    uint2 rs = *reinterpret_cast<const uint2*>(H + (size_t)n * D + l * 4);
    const __half2* hsp = reinterpret_cast<const __half2*>(&rs);
    float2 ha = __half22float2(hsp[0]), hb = __half22float2(hsp[1]);
    float4 bv = *reinterpret_cast<const float4*>(bias + l * 4);
    float4 v;
    v.x = fmaf(ha.x, dii, acc.x) + bv.x;
    v.y = fmaf(ha.y, dii, acc.y) + bv.y;
    v.z = fmaf(hb.x, dii, acc.z) + bv.z;
    v.w = fmaf(hb.y, dii, acc.w) + bv.w;
    if (DO_RELU) {
      v.x = fmaxf(v.x, 0.f); v.y = fmaxf(v.y, 0.f);
      v.z = fmaxf(v.z, 0.f); v.w = fmaxf(v.w, 0.f);
    }
    if constexpr (std::is_same<TO, float>::value) {
      *reinterpret_cast<float4*>(out + (size_t)n * D + l * 4) = v;
    } else {
      uint2 pk;
      __half2 q0 = __floats2half2_rn(v.x, v.y);
      __half2 q1 = __floats2half2_rn(v.z, v.w);
      pk.x = *reinterpret_cast<unsigned int*>(&q0);
      pk.y = *reinterpret_cast<unsigned int*>(&q1);
      *reinterpret_cast<uint2*>((__half*)out + (size_t)n * D + l * 4) = pk;
    }
  }
}

// ---- launch ---------------------------------------------------------------

extern "C" void kernel_launch(void* const* d_in, const int* in_sizes, int n_in,
                              void* d_out, int out_size, void* d_ws, size_t ws_size,
                              hipStream_t stream) {
  const float* x  = (const float*)d_in[0];
  const int* edge = (const int*)d_in[1];
  const float* W1 = (const float*)d_in[2];
  const float* b1 = (const float*)d_in[3];
  const float* W2 = (const float*)d_in[4];
  const float* b2 = (const float*)d_in[5];
  const int N = in_sizes[0] / D;   // 50000
  const int E = in_sizes[1] / 2;   // 1.6M
  const int* srcp = edge;
  const int* dstp = edge + E;
  float* out = (float*)d_out;

  const int M  = N * NCH;
  const int MP = (M + 1023) & ~1023;
  const int SB = MP / 1024;

  auto align = [](size_t v) { return (v + 255) & ~(size_t)255; };
  char* ws = (char*)d_ws;
  size_t o = 0;
  int*   deg2    = (int*)(ws + o);          o += align((size_t)MP * 4);
  int*   bsum    = (int*)(ws + o);          o += align((size_t)SB * 4);
  int*   offsets = (int*)(ws + o);          o += align((size_t)(M + 1) * 4);
  int*   rank    = (int*)(ws + o);          o += align((size_t)E * 4);
  float* dinv    = (float*)(ws + o);        o += align((size_t)N * 4);
  unsigned int* csr = (unsigned int*)(ws + o); o += align((size_t)E * 4);
  __half* Hh     = (__half*)(ws + o);       o += align((size_t)N * D * 2);
  __half* h1h    = (__half*)(ws + o);       o += align((size_t)N * D * 2);

  // CSR build (chunked by src>>14, packed entries)
  hipMemsetAsync(deg2, 0, (size_t)MP * 4, stream);
  deg2_kernel<<<(E + 255) / 256, 256, 0, stream>>>(srcp, dstp, deg2, rank, E);
  bsum_kernel<<<SB, 256, 0, stream>>>(deg2, bsum);
  scan2_kernel<<<SB, 256, 0, stream>>>(deg2, bsum, offsets, M, E);
  dinv_kernel<<<(N + 255) / 256, 256, 0, stream>>>(offsets, dinv, N);
  place_kernel<<<(E + 255) / 256, 256, 0, stream>>>(srcp, dstp, rank, offsets, dinv, csr, E);

  int gemm_blocks = (N + 31) / 32;
  int agg_blocks = (N + 3) / 4;

  // layer 1: h1 = relu(A @ (x@W1) + b1)   (fp16 intermediates)
  gemm_kernel<float><<<gemm_blocks, 256, 0, stream>>>(x, W1, Hh, N);
  agg_kernel<1, __half><<<agg_blocks, 256, 0, stream>>>(Hh, offsets, csr, dinv, b1, h1h, N);

  // layer 2: z = A @ (h1@W2) + b2  -> f32 d_out
  gemm_kernel<__half><<<gemm_blocks, 256, 0, stream>>>(h1h, W2, Hh, N);
  agg_kernel<0, float><<<agg_blocks, 256, 0, stream>>>(Hh, offsets, csr, dinv, b2, out, N);
}

// Round 7
// 282.837 us; speedup vs baseline: 2.7124x; 1.1211x over previous
//
#include <hip/hip_runtime.h>
#include <hip/hip_fp16.h>
#include <type_traits>

#define D 128

// ---- degree histogram + per-edge rank ------------------------------------

__global__ __launch_bounds__(256) void deg_kernel(const int* __restrict__ dst,
                                                  int* __restrict__ deg,
                                                  int* __restrict__ rank, int E) {
  int e = blockIdx.x * 256 + threadIdx.x;
  if (e >= E) return;
  rank[e] = atomicAdd(&deg[dst[e]], 1);
}

// ---- parallel scan stage 1: per-1024-chunk sums ---------------------------

__global__ __launch_bounds__(256) void bsum_kernel(const int* __restrict__ deg,
                                                   int* __restrict__ bsum) {
  __shared__ int ws[4];
  int i0 = blockIdx.x * 1024 + threadIdx.x * 4;
  int4 v = *reinterpret_cast<const int4*>(deg + i0);   // zero-padded
  int s = v.x + v.y + v.z + v.w;
  #pragma unroll
  for (int off = 32; off; off >>= 1) s += __shfl_down(s, off);
  if ((threadIdx.x & 63) == 0) ws[threadIdx.x >> 6] = s;
  __syncthreads();
  if (threadIdx.x == 0) bsum[blockIdx.x] = ws[0] + ws[1] + ws[2] + ws[3];
}

// ---- parallel scan stage 2: exclusive offsets + fused dinv ----------------

__global__ __launch_bounds__(256) void scan_kernel(const int* __restrict__ deg,
                                                   const int* __restrict__ bsum,
                                                   int* __restrict__ offsets,
                                                   float* __restrict__ dinv,
                                                   int N, int E) {
  __shared__ int ts[256];
  int b = blockIdx.x;
  int base = 0;
  for (int t = 0; t < b; ++t) base += bsum[t];

  int i0 = b * 1024 + threadIdx.x * 4;
  int4 v = *reinterpret_cast<const int4*>(deg + i0);
  int t4 = v.x + v.y + v.z + v.w;
  ts[threadIdx.x] = t4;
  __syncthreads();
  #pragma unroll
  for (int off = 1; off < 256; off <<= 1) {
    int u = (threadIdx.x >= off) ? ts[threadIdx.x - off] : 0;
    __syncthreads();
    ts[threadIdx.x] += u;
    __syncthreads();
  }
  int run = base + ts[threadIdx.x] - t4;

  int dd[4] = {v.x, v.y, v.z, v.w};
  #pragma unroll
  for (int k = 0; k < 4; ++k) {
    int i = i0 + k;
    if (i < N) {
      offsets[i] = run;
      dinv[i] = rsqrtf(1.0f + (float)dd[k]);
    }
    run += dd[k];
  }
  if (b == 0 && threadIdx.x == 0) offsets[N] = E;
}

// ---- atomic-free placement; pack {src:17, norm_q15:15} into 4 B ----------

__global__ __launch_bounds__(256) void place_kernel(const int* __restrict__ src,
                                                    const int* __restrict__ dst,
                                                    const int* __restrict__ rank,
                                                    const int* __restrict__ offsets,
                                                    const float* __restrict__ dinv,
                                                    unsigned int* __restrict__ csr, int E) {
  int e = blockIdx.x * 256 + threadIdx.x;
  if (e >= E) return;
  int s = src[e];
  int d = dst[e];
  int pos = offsets[d] + rank[e];
  float nm = dinv[s] * dinv[d];                         // in (0, 1]
  unsigned int q = (unsigned int)__float2int_rn(nm * 32767.0f);
  csr[pos] = ((unsigned int)s << 15) | q;
}

// ---- GEMM: H[N,128](fp16) = X[N,128] @ W[128,128] -------------------------

template <typename TI>
__global__ __launch_bounds__(256) void gemm_kernel(const TI* __restrict__ X,
                                                   const float* __restrict__ W,
                                                   __half* __restrict__ H, int N) {
  __shared__ float xs[32 * D];
  int row0 = blockIdx.x * 32;
  if constexpr (std::is_same<TI, float>::value) {
    #pragma unroll
    for (int jj = 0; jj < 4; ++jj) {
      int f4 = threadIdx.x + jj * 256;
      int r = f4 >> 5;
      float4 v = make_float4(0.f, 0.f, 0.f, 0.f);
      if (row0 + r < N) v = *reinterpret_cast<const float4*>(X + (size_t)row0 * D + (size_t)f4 * 4);
      *reinterpret_cast<float4*>(xs + f4 * 4) = v;
    }
  } else {
    #pragma unroll
    for (int jj = 0; jj < 2; ++jj) {
      int g8 = threadIdx.x + jj * 256;
      int r = g8 >> 4;
      uint4 raw = make_uint4(0u, 0u, 0u, 0u);
      if (row0 + r < N)
        raw = *reinterpret_cast<const uint4*>((const __half*)X + (size_t)row0 * D + (size_t)g8 * 8);
      const __half2* hp = reinterpret_cast<const __half2*>(&raw);
      float* dst8 = xs + (size_t)g8 * 8;
      #pragma unroll
      for (int k = 0; k < 4; ++k) {
        float2 f = __half22float2(hp[k]);
        dst8[k * 2] = f.x;
        dst8[k * 2 + 1] = f.y;
      }
    }
  }
  __syncthreads();

  int tx = threadIdx.x & 63;
  int ty = threadIdx.x >> 6;
  int c0 = tx * 2;
  float2 acc[8];
  #pragma unroll
  for (int r = 0; r < 8; ++r) acc[r] = make_float2(0.f, 0.f);
  const float* xbase = xs + ty * 8 * D;

  for (int k = 0; k < D; k += 4) {
    float2 w0 = *reinterpret_cast<const float2*>(W + (size_t)(k + 0) * D + c0);
    float2 w1 = *reinterpret_cast<const float2*>(W + (size_t)(k + 1) * D + c0);
    float2 w2 = *reinterpret_cast<const float2*>(W + (size_t)(k + 2) * D + c0);
    float2 w3 = *reinterpret_cast<const float2*>(W + (size_t)(k + 3) * D + c0);
    #pragma unroll
    for (int r = 0; r < 8; ++r) {
      float4 xv = *reinterpret_cast<const float4*>(xbase + r * D + k);
      acc[r].x = fmaf(xv.x, w0.x, acc[r].x); acc[r].y = fmaf(xv.x, w0.y, acc[r].y);
      acc[r].x = fmaf(xv.y, w1.x, acc[r].x); acc[r].y = fmaf(xv.y, w1.y, acc[r].y);
      acc[r].x = fmaf(xv.z, w2.x, acc[r].x); acc[r].y = fmaf(xv.z, w2.y, acc[r].y);
      acc[r].x = fmaf(xv.w, w3.x, acc[r].x); acc[r].y = fmaf(xv.w, w3.y, acc[r].y);
    }
  }

  #pragma unroll
  for (int r = 0; r < 8; ++r) {
    int row = row0 + ty * 8 + r;
    if (row < N)
      *reinterpret_cast<__half2*>(H + (size_t)row * D + c0) = __floats2half2_rn(acc[r].x, acc[r].y);
  }
}

// ---- Aggregation: one wave per dst node -----------------------------------
// 4 edge-groups (g = lane>>4) x 16 feature-lanes (l = lane&15, 8 halves each).
// Group g: edges beg+g, beg+g+4, ... unroll-2 -> up to 8 row-gathers in flight.

template <int DO_RELU, typename TO>
__global__ __launch_bounds__(256) void agg_kernel(const __half* __restrict__ H,
                                                  const int* __restrict__ offsets,
                                                  const unsigned int* __restrict__ csr,
                                                  const float* __restrict__ dinv,
                                                  const float* __restrict__ bias,
                                                  TO* __restrict__ out, int N) {
  int n = blockIdx.x * 4 + (threadIdx.x >> 6);
  if (n >= N) return;
  int lane = threadIdx.x & 63;
  int g = lane >> 4;
  int l = lane & 15;

  int beg = offsets[n];
  int end = offsets[n + 1];

  float acc[8];
  #pragma unroll
  for (int k = 0; k < 8; ++k) acc[k] = 0.f;

  const __half* Hl = H + l * 8;

  int j = beg + g;
  for (; j + 4 < end; j += 8) {
    unsigned int p0 = csr[j];
    unsigned int p1 = csr[j + 4];
    float m0 = (float)(p0 & 0x7fffu) * (1.0f / 32767.0f);
    float m1 = (float)(p1 & 0x7fffu) * (1.0f / 32767.0f);
    uint4 r0 = *reinterpret_cast<const uint4*>(Hl + (size_t)(p0 >> 15) * D);
    uint4 r1 = *reinterpret_cast<const uint4*>(Hl + (size_t)(p1 >> 15) * D);
    const __half2* h0 = reinterpret_cast<const __half2*>(&r0);
    const __half2* h1 = reinterpret_cast<const __half2*>(&r1);
    #pragma unroll
    for (int k = 0; k < 4; ++k) {
      float2 f0 = __half22float2(h0[k]);
      float2 f1 = __half22float2(h1[k]);
      acc[2 * k]     = fmaf(f0.x, m0, acc[2 * k]);
      acc[2 * k + 1] = fmaf(f0.y, m0, acc[2 * k + 1]);
      acc[2 * k]     = fmaf(f1.x, m1, acc[2 * k]);
      acc[2 * k + 1] = fmaf(f1.y, m1, acc[2 * k + 1]);
    }
  }
  if (j < end) {
    unsigned int p0 = csr[j];
    float m0 = (float)(p0 & 0x7fffu) * (1.0f / 32767.0f);
    uint4 r0 = *reinterpret_cast<const uint4*>(Hl + (size_t)(p0 >> 15) * D);
    const __half2* h0 = reinterpret_cast<const __half2*>(&r0);
    #pragma unroll
    for (int k = 0; k < 4; ++k) {
      float2 f0 = __half22float2(h0[k]);
      acc[2 * k]     = fmaf(f0.x, m0, acc[2 * k]);
      acc[2 * k + 1] = fmaf(f0.y, m0, acc[2 * k + 1]);
    }
  }

  #pragma unroll
  for (int k = 0; k < 8; ++k) {
    acc[k] += __shfl_xor(acc[k], 16);
    acc[k] += __shfl_xor(acc[k], 32);
  }

  if (g == 0) {
    float di = dinv[n];
    float dii = di * di;
    uint4 rs = *reinterpret_cast<const uint4*>(Hl + (size_t)n * D);
    const __half2* hs = reinterpret_cast<const __half2*>(&rs);
    float4 bv0 = *reinterpret_cast<const float4*>(bias + l * 8);
    float4 bv1 = *reinterpret_cast<const float4*>(bias + l * 8 + 4);
    float v[8];
    #pragma unroll
    for (int k = 0; k < 4; ++k) {
      float2 f = __half22float2(hs[k]);
      v[2 * k]     = fmaf(f.x, dii, acc[2 * k]);
      v[2 * k + 1] = fmaf(f.y, dii, acc[2 * k + 1]);
    }
    v[0] += bv0.x; v[1] += bv0.y; v[2] += bv0.z; v[3] += bv0.w;
    v[4] += bv1.x; v[5] += bv1.y; v[6] += bv1.z; v[7] += bv1.w;
    if (DO_RELU) {
      #pragma unroll
      for (int k = 0; k < 8; ++k) v[k] = fmaxf(v[k], 0.f);
    }
    if constexpr (std::is_same<TO, float>::value) {
      float4 o0 = make_float4(v[0], v[1], v[2], v[3]);
      float4 o1 = make_float4(v[4], v[5], v[6], v[7]);
      *reinterpret_cast<float4*>(out + (size_t)n * D + l * 8) = o0;
      *reinterpret_cast<float4*>(out + (size_t)n * D + l * 8 + 4) = o1;
    } else {
      uint4 pk;
      __half2 q0 = __floats2half2_rn(v[0], v[1]);
      __half2 q1 = __floats2half2_rn(v[2], v[3]);
      __half2 q2 = __floats2half2_rn(v[4], v[5]);
      __half2 q3 = __floats2half2_rn(v[6], v[7]);
      pk.x = *reinterpret_cast<unsigned int*>(&q0);
      pk.y = *reinterpret_cast<unsigned int*>(&q1);
      pk.z = *reinterpret_cast<unsigned int*>(&q2);
      pk.w = *reinterpret_cast<unsigned int*>(&q3);
      *reinterpret_cast<uint4*>((__half*)out + (size_t)n * D + l * 8) = pk;
    }
  }
}

// ---- launch ---------------------------------------------------------------

extern "C" void kernel_launch(void* const* d_in, const int* in_sizes, int n_in,
                              void* d_out, int out_size, void* d_ws, size_t ws_size,
                              hipStream_t stream) {
  const float* x  = (const float*)d_in[0];
  const int* edge = (const int*)d_in[1];
  const float* W1 = (const float*)d_in[2];
  const float* b1 = (const float*)d_in[3];
  const float* W2 = (const float*)d_in[4];
  const float* b2 = (const float*)d_in[5];
  const int N = in_sizes[0] / D;   // 50000
  const int E = in_sizes[1] / 2;   // 1.6M
  const int* srcp = edge;
  const int* dstp = edge + E;
  float* out = (float*)d_out;

  const int NP = (N + 1023) & ~1023;
  const int SB = NP / 1024;

  auto align = [](size_t v) { return (v + 255) & ~(size_t)255; };
  char* ws = (char*)d_ws;
  size_t o = 0;
  int*   deg     = (int*)(ws + o);             o += align((size_t)NP * 4);
  int*   bsum    = (int*)(ws + o);             o += align((size_t)SB * 4);
  int*   offsets = (int*)(ws + o);             o += align((size_t)(N + 1) * 4);
  int*   rank    = (int*)(ws + o);             o += align((size_t)E * 4);
  float* dinv    = (float*)(ws + o);           o += align((size_t)N * 4);
  unsigned int* csr = (unsigned int*)(ws + o); o += align((size_t)E * 4);
  __half* Hh     = (__half*)(ws + o);          o += align((size_t)N * D * 2);
  __half* h1h    = (__half*)(ws + o);          o += align((size_t)N * D * 2);

  // CSR build
  hipMemsetAsync(deg, 0, (size_t)NP * 4, stream);
  deg_kernel<<<(E + 255) / 256, 256, 0, stream>>>(dstp, deg, rank, E);
  bsum_kernel<<<SB, 256, 0, stream>>>(deg, bsum);
  scan_kernel<<<SB, 256, 0, stream>>>(deg, bsum, offsets, dinv, N, E);
  place_kernel<<<(E + 255) / 256, 256, 0, stream>>>(srcp, dstp, rank, offsets, dinv, csr, E);

  int gemm_blocks = (N + 31) / 32;
  int agg_blocks = (N + 3) / 4;

  // layer 1: h1 = relu(A @ (x@W1) + b1)   (fp16 intermediates)
  gemm_kernel<float><<<gemm_blocks, 256, 0, stream>>>(x, W1, Hh, N);
  agg_kernel<1, __half><<<agg_blocks, 256, 0, stream>>>(Hh, offsets, csr, dinv, b1, h1h, N);

  // layer 2: z = A @ (h1@W2) + b2  -> f32 d_out
  gemm_kernel<__half><<<gemm_blocks, 256, 0, stream>>>(h1h, W2, Hh, N);
  agg_kernel<0, float><<<agg_blocks, 256, 0, stream>>>(Hh, offsets, csr, dinv, b2, out, N);
}